// Round 4
// baseline (501.065 us; speedup 1.0000x reference)
//
#include <hip/hip_runtime.h>

typedef unsigned short u16;
typedef unsigned int   u32;

using bf16x8 = __attribute__((ext_vector_type(8))) __bf16;
using f32x4  = __attribute__((ext_vector_type(4))) float;

__device__ __forceinline__ float bf2f(u16 h){ return __uint_as_float(((u32)h) << 16); }
__device__ __forceinline__ u16 f2bf(float f){
    u32 u = __float_as_uint(f);
    u32 r = u + 0x7FFFu + ((u >> 16) & 1u);   // round-to-nearest-even
    return (u16)(r >> 16);
}

// async global->LDS, 16B per lane; LDS dest = wave-uniform base + lane*16.
__device__ __forceinline__ void async16(const void* g, void* l){
    __builtin_amdgcn_global_load_lds(
        (const __attribute__((address_space(1))) unsigned int*)g,
        (__attribute__((address_space(3))) unsigned int*)l, 16, 0, 0);
}
__device__ __forceinline__ bf16x8 cvt8(uint4 v){
    union { uint4 u; bf16x8 b; } c; c.u = v; return c.b;
}

// ---------------------------------------------------------------------------
// Block 0: dtype probe (wave-parallel). flags[0]=1 if floats are bf16;
// flags[1]=mask dtype 0=u8,1=i32,2=bf16,3=f32.
// Block 1: label grouping: slot_of_node[n] = label*128+rank (<128) else
// 384+ovf_rank; ovf_flag = #overflow nodes.
// ---------------------------------------------------------------------------
__global__ void probe_and_perm(const void* x, const void* masks, int* flags,
                               const int* labels, int* slot_of_node, int* ovf_flag)
{
    if (blockIdx.x == 0){
        int l = threadIdx.x;
        if (l < 64){
            const u16* hx = (const u16*)x;
            int e0 = (hx[l] >> 7) & 0xFF;
            int e1 = (hx[l + 64] >> 7) & 0xFF;
            unsigned long long b0 = __ballot(e0 >= 100 && e0 <= 140);
            unsigned long long b1 = __ballot(e1 >= 100 && e1 <= 140);
            int cnt = __popcll(b0) + __popcll(b1);
            const u32* w  = (const u32*)masks;
            const u16* hm = (const u16*)masks;
            u32 v = w[l];
            unsigned long long i32bad = __ballot(v > 1u);
            unsigned long long f32bad = __ballot(v != 0u && v != 0x3F800000u);
            u16 h0 = hm[l], h1 = hm[l + 64];
            unsigned long long bfbad =
                __ballot((h0 != 0 && h0 != 0x3F80) || (h1 != 0 && h1 != 0x3F80));
            if (l == 0){
                flags[0] = (cnt >= 100) ? 1 : 0;
                int md = 0;
                if (!i32bad) md = 1; else if (!f32bad) md = 3; else if (!bfbad) md = 2;
                flags[1] = md;
            }
        }
        return;
    }
    // perm block
    __shared__ int lab[300];
    __shared__ unsigned char sp[300];
    int t = threadIdx.x;
    if (t < 300) lab[t] = labels[t];
    __syncthreads();
    int r = 0;
    if (t < 300){
        int k = lab[t];
        for (int j = 0; j < t; j++) r += (lab[j] == k);
        sp[t] = (r >= 128) ? 1 : 0;
    }
    __syncthreads();
    if (t < 300){
        if (!sp[t]) slot_of_node[t] = lab[t] * 128 + r;
        else {
            int so = 0;
            for (int j = 0; j < t; j++) so += sp[j];
            slot_of_node[t] = 384 + so;
        }
    }
    if (t == 0){
        int tot = 0;
        for (int j = 0; j < 300; j++) tot += sp[j];
        *ovf_flag = tot;
    }
}

// ---------------------------------------------------------------------------
// Transpose + convert to bf16, 3 sources via blockIdx.z; zero-pads j >= J.
// ---------------------------------------------------------------------------
__global__ void trans_cvt_f3(const void* s0, const void* s1, const void* s2,
                             u16* dst, size_t dstride, int I, int J, int ldd,
                             const int* flags)
{
    __shared__ float tile[32][33];
    const void* src = (blockIdx.z == 0) ? s0 : (blockIdx.z == 1) ? s1 : s2;
    u16* d = dst + (size_t)blockIdx.z * dstride;
    int j0 = blockIdx.x * 32, i0 = blockIdx.y * 32;
    int tx = threadIdx.x, ty = threadIdx.y;
    bool isbf = (flags[0] != 0);
    #pragma unroll
    for (int s = 0; s < 32; s += 8){
        int i = i0 + ty + s, j = j0 + tx;
        float v = 0.f;
        if (j < J){
            size_t idx = (size_t)i * J + j;
            v = isbf ? bf2f(((const u16*)src)[idx]) : ((const float*)src)[idx];
        }
        tile[ty + s][tx] = v;
    }
    __syncthreads();
    #pragma unroll
    for (int s = 0; s < 32; s += 8){
        int j = j0 + ty + s, i = i0 + tx;
        d[(size_t)j * ldd + i] = f2bf(tile[tx][ty + s]);
    }
}

__global__ void pack_biases(const void* a0, const void* a1, const void* a2,
                            const void* c0, const void* c1, const void* c2,
                            float* b1f, float* b2f, const int* flags)
{
    int idx = blockIdx.x * 256 + threadIdx.x;
    if (idx >= 3072) return;
    int k = idx >> 10, r = idx & 1023;
    bool isbf = (flags[0] != 0);
    const void* p1 = (k == 0) ? a0 : (k == 1) ? a1 : a2;
    const void* p2 = (k == 0) ? c0 : (k == 1) ? c1 : c2;
    b1f[idx] = isbf ? bf2f(((const u16*)p1)[r]) : ((const float*)p1)[r];
    b2f[idx] = isbf ? bf2f(((const u16*)p2)[r]) : ((const float*)p2)[r];
}

// ---------------------------------------------------------------------------
// masks [P][NN] -> mfT[slot][p] bf16 {0,1}, rows permuted by slot_of_node,
// fused per-slot popcount into counts (float, atomic). Block: 128 p x 32 n.
// md==0 fast path: u32 loads (4 bytes of n each). Stores: uint4 coalesced.
// ---------------------------------------------------------------------------
__global__ void trans_mask_count(const void* src, u16* dst,
                                 const int* slot_of_node, float* counts,
                                 const int* flags)
{
    constexpr int NN_ = 300, P_ = 40000, LDP = 40064;
    __shared__ u16 tile[128][33];    // [p_in][n_in]
    __shared__ int slt[32];
    const int p0 = blockIdx.x * 128, n0 = blockIdx.y * 32;
    const int tid = threadIdx.x;
    const int md = flags[1];
    if (tid < 32) slt[tid] = (n0 + tid < NN_) ? slot_of_node[n0 + tid] : -1;

    if (md == 0){
        const unsigned char* s8 = (const unsigned char*)src;
        const int tx = tid & 7, ty = tid >> 3;   // tx: n-word, ty: p 0..31
        #pragma unroll
        for (int rep = 0; rep < 4; rep++){
            const int p = p0 + rep * 32 + ty;
            const int nb = n0 + tx * 4;
            u32 w = 0;
            if (p < P_){
                if (nb + 3 < NN_)
                    w = *(const u32*)(s8 + (size_t)p * NN_ + nb);
                else {
                    for (int b = 0; b < 4; b++)
                        if (nb + b < NN_)
                            w |= (u32)s8[(size_t)p * NN_ + nb + b] << (8 * b);
                }
            }
            #pragma unroll
            for (int b = 0; b < 4; b++)
                tile[rep * 32 + ty][tx * 4 + b] =
                    ((w >> (8 * b)) & 0xFFu) ? (u16)0x3F80 : (u16)0;
        }
    } else {
        #pragma unroll
        for (int it = 0; it < 16; it++){
            const int e = tid + it * 256;
            const int n_in = e & 31, p_in = e >> 5;
            const int p = p0 + p_in, n = n0 + n_in;
            u16 v = 0;
            if (p < P_ && n < NN_){
                size_t idx = (size_t)p * NN_ + n;
                bool on;
                if (md == 1)      on = ((const int*)src)[idx] != 0;
                else if (md == 2) on = ((const u16*)src)[idx] != 0;
                else              on = ((const float*)src)[idx] != 0.f;
                v = on ? (u16)0x3F80 : (u16)0;
            }
            tile[p_in][n_in] = v;
        }
    }
    __syncthreads();

    // store: 32 rows (n) x 16 positions of 16B, two halves
    #pragma unroll
    for (int half = 0; half < 2; half++){
        const int row = tid >> 3;
        const int pos = (tid & 7) + half * 8;
        const int slot = slt[row];
        if (slot >= 0){
            union { u16 h[8]; uint4 v; } tmp;
            #pragma unroll
            for (int j = 0; j < 8; j++) tmp.h[j] = tile[pos * 8 + j][row];
            *reinterpret_cast<uint4*>(&dst[(size_t)slot * LDP + p0 + pos * 8]) = tmp.v;
        }
    }
    // count
    if (tid < 32){
        const int slot = slt[tid];
        if (slot >= 0){
            int c = 0;
            for (int p = 0; p < 128; p++) c += (tile[p][tid] != 0);
            if (c > 0) atomicAdd(&counts[slot], (float)c);
        }
    }
}

// ---------------------------------------------------------------------------
// FUSED L1 + mask-sum, v2: single-barrier double-buffered staging, mask
// fragments prefetched to registers, XCD-aware id swizzle (MAP 0).
// Per block: one m-tile (128 of 3072 L1 rows, branch = bx>>3) x 15 p-tiles.
//   stage-1: H = relu(B1T[m-tile] . feat[p-tile]^T + b1)  (K=256, dbuf LDS)
//   repack:  H -> Hs[pc][128][32], XOR-swizzled by (m>>2)&3
//   stage-2: acc2[slot][m] += mask . H^T (K=128, mask frags in registers)
// MAP 0: grouped slots, sums=[3*128][1024]; MAP 1: overflow, sums=[128][3072].
// ---------------------------------------------------------------------------
template<int MAP>
__global__ __launch_bounds__(256, 2)
void fused_l1_mask(const u16* __restrict__ B1T, const u16* __restrict__ feat,
                   const u16* __restrict__ mfT, const float* __restrict__ b1f,
                   float* __restrict__ sums, const int* __restrict__ skipf)
{
    if constexpr (MAP == 1){ if (*skipf == 0) return; }
    constexpr int PPAD = 40064;
    __shared__ __align__(16) u16 As[2][4096];   // 16 KB
    __shared__ __align__(16) u16 Bs[2][4096];   // 16 KB
    __shared__ __align__(16) u16 Hs[16384];     // 32 KB

    int bx, ts, te;
    if constexpr (MAP == 0){
        // swizzle: the 8 same-branch/same-p blocks get ids == r (mod 8) -> one XCD
        const int id = blockIdx.x;
        const int r = id & 7, qq = id >> 3;
        const int j = (qq >> 3) * 8 + r;        // combo = branch*22 + y
        if (j >= 66) return;
        const int sub = qq & 7;
        const int branch = j / 22, y = j % 22;
        bx = branch * 8 + sub;
        ts = y * 15; te = ts + 15; if (te > 313) te = 313;
        if (ts >= te) return;
    } else {
        bx = blockIdx.x;
        ts = blockIdx.y * 40; te = ts + 40; if (te > 313) te = 313;
        if (ts >= te) return;
    }
    const int m0 = bx * 128;
    const int srow = (MAP == 0) ? ((bx >> 3) * 128) : 384;

    const int tid = threadIdx.x;
    const int wave = tid >> 6, lane = tid & 63;
    const int wr = wave >> 1, wc = wave & 1;
    const int t = lane & 15, q = lane >> 4;

    float bv[4][4];
    #pragma unroll
    for (int mi = 0; mi < 4; mi++)
        #pragma unroll
        for (int i = 0; i < 4; i++)
            bv[mi][i] = b1f[m0 + wr*64 + mi*16 + q*4 + i];

    const int cr = lane >> 2, cp = lane & 3;
    const int ca = wave*2, cb = wave*2 + 1;
    const u16* gA0 = B1T + (size_t)(m0 + ca*16 + cr)*256 + cp*8;
    const u16* gA1 = B1T + (size_t)(m0 + cb*16 + cr)*256 + cp*8;
    const u16* gBb = feat + (size_t)(ca*16 + cr)*256 + cp*8;
    const u16* gBc = feat + (size_t)(cb*16 + cr)*256 + cp*8;
    const u16* mrow = mfT + (size_t)(srow + wr*64 + t) * PPAD;

    f32x4 acc2[4][4];
    #pragma unroll
    for (int a = 0; a < 4; a++)
        #pragma unroll
        for (int b = 0; b < 4; b++)
            #pragma unroll
            for (int e = 0; e < 4; e++) acc2[a][b][e] = 0.f;

    // prefetch p-tile ts, kt=0 into buffer 0
    {
        const size_t pofs = (size_t)ts * 128 * 256;
        async16(gA0, &As[0][ca*512]);
        async16(gA1, &As[0][cb*512]);
        async16(gBb + pofs, &Bs[0][ca*512]);
        async16(gBc + pofs, &Bs[0][cb*512]);
    }

    for (int pt = ts; pt < te; ++pt){
        const int p0 = pt * 128;
        const size_t pofs = (size_t)p0 * 256;

        f32x4 acc1[4][4];
        #pragma unroll
        for (int a = 0; a < 4; a++)
            #pragma unroll
            for (int b = 0; b < 4; b++)
                #pragma unroll
                for (int e = 0; e < 4; e++) acc1[a][b][e] = 0.f;

        uint4 mcur[4], mnxt[4];

        #pragma unroll
        for (int kt = 0; kt < 8; ++kt){
            __syncthreads();               // buf[kt&1] ready for everyone
            const int cur = kt & 1;
            if (kt < 7){
                const int nxt = cur ^ 1;
                const size_t ko = (size_t)(kt + 1) * 32;
                async16(gA0 + ko, &As[nxt][ca*512]);
                async16(gA1 + ko, &As[nxt][cb*512]);
                async16(gBb + pofs + ko, &Bs[nxt][ca*512]);
                async16(gBc + pofs + ko, &Bs[nxt][cb*512]);
            } else {
                // prefetch mask pc=0 fragments (drained at next barrier)
                #pragma unroll
                for (int mi = 0; mi < 4; mi++)
                    mcur[mi] = *reinterpret_cast<const uint4*>(
                        mrow + (size_t)(mi*16)*PPAD + p0 + q*8);
            }
            bf16x8 af[4], bg[4];
            #pragma unroll
            for (int mi = 0; mi < 4; mi++)
                af[mi] = *reinterpret_cast<const bf16x8*>(
                    &As[cur][(wr*64 + mi*16 + t)*32 + q*8]);
            #pragma unroll
            for (int ni = 0; ni < 4; ni++)
                bg[ni] = *reinterpret_cast<const bf16x8*>(
                    &Bs[cur][(wc*64 + ni*16 + t)*32 + q*8]);
            #pragma unroll
            for (int mi = 0; mi < 4; mi++)
                #pragma unroll
                for (int ni = 0; ni < 4; ni++)
                    acc1[mi][ni] = __builtin_amdgcn_mfma_f32_16x16x32_bf16(
                        af[mi], bg[ni], acc1[mi][ni], 0, 0, 0);
        }

        __syncthreads();   // all waves done reading Hs from prev stage-2

        // epilogue: bias+relu, H -> Hs with XOR swizzle ((m_l>>2)&3 == q)
        #pragma unroll
        for (int mi = 0; mi < 4; mi++){
            #pragma unroll
            for (int i = 0; i < 4; i++){
                const int m_l = wr*64 + mi*16 + q*4 + i;
                const float bb = bv[mi][i];
                #pragma unroll
                for (int ni = 0; ni < 4; ni++){
                    const int p_l = wc*64 + ni*16 + t;
                    float v = acc1[mi][ni][i] + bb;
                    v = (v > 0.f) ? v : 0.f;
                    const int pc = p_l >> 5, pin = p_l & 31;
                    const int cg = (pin >> 3) ^ q;
                    Hs[pc*4096 + m_l*32 + cg*8 + (pin & 7)] = f2bf(v);
                }
            }
        }
        __syncthreads();

        // prefetch next p-tile kt=0 (overlaps stage-2; buf0 unused now)
        if (pt + 1 < te){
            const size_t pofs2 = (size_t)(pt + 1) * 128 * 256;
            async16(gA0, &As[0][ca*512]);
            async16(gA1, &As[0][cb*512]);
            async16(gBb + pofs2, &Bs[0][ca*512]);
            async16(gBc + pofs2, &Bs[0][cb*512]);
        }

        // stage-2: acc2 += mask . H^T, K=128 in 4 chunks; mask pipelined
        #pragma unroll
        for (int pc = 0; pc < 4; ++pc){
            if (pc < 3){
                #pragma unroll
                for (int mi = 0; mi < 4; mi++)
                    mnxt[mi] = *reinterpret_cast<const uint4*>(
                        mrow + (size_t)(mi*16)*PPAD + p0 + (pc+1)*32 + q*8);
            }
            bf16x8 hb[4];
            #pragma unroll
            for (int ni = 0; ni < 4; ni++){
                const int row = wc*64 + ni*16 + t;
                hb[ni] = *reinterpret_cast<const bf16x8*>(
                    &Hs[pc*4096 + row*32 + ((q ^ (t >> 2)) * 8)]);
            }
            #pragma unroll
            for (int mi = 0; mi < 4; mi++)
                #pragma unroll
                for (int ni = 0; ni < 4; ni++)
                    acc2[mi][ni] = __builtin_amdgcn_mfma_f32_16x16x32_bf16(
                        cvt8(mcur[mi]), hb[ni], acc2[mi][ni], 0, 0, 0);
            if (pc < 3){
                #pragma unroll
                for (int mi = 0; mi < 4; mi++) mcur[mi] = mnxt[mi];
            }
        }
    }

    // dump accumulators (rows = slots, cols = m)
    #pragma unroll
    for (int mi = 0; mi < 4; mi++){
        #pragma unroll
        for (int i = 0; i < 4; i++){
            const int slot_l = wr*64 + mi*16 + q*4 + i;
            #pragma unroll
            for (int ni = 0; ni < 4; ni++){
                const int m_l = wc*64 + ni*16 + t;
                const float v = acc2[mi][ni][i];
                if constexpr (MAP == 0)
                    atomicAdd(sums + (size_t)((bx>>3)*128 + slot_l)*1024
                                   + (bx&7)*128 + m_l, v);
                else
                    atomicAdd(sums + (size_t)slot_l*3072 + bx*128 + m_l, v);
            }
        }
    }
}

// ---------------------------------------------------------------------------
// NT GEMM for the small L2 layers (MAP==3 batched over blockIdx.z).
// ---------------------------------------------------------------------------
template<int BIAS_MODE, bool RELU, int OUT_MODE, int MAP>
__global__ __launch_bounds__(256)
void gemm_nt(const u16* __restrict__ A, int lda,
             const u16* __restrict__ B, int ldb,
             void* __restrict__ Cp, int ldc,
             const float* __restrict__ bias,
             int kIters, int kChunk,
             const int* __restrict__ skipf,
             long abatch, long bbatch, long cbatch, long bbias)
{
    if (skipf && *skipf == 0) return;
    __shared__ __align__(16) u16 sh[8704];
    u16* As = sh;
    u16* Bs = sh + 4096;

    const int tid  = threadIdx.x;
    const int wave = tid >> 6, lane = tid & 63;
    const int wr = wave >> 1, wc = wave & 1;
    const int t = lane & 15, q = lane >> 4;

    int m0, n0;
    if constexpr (MAP == 1){ m0 = blockIdx.x * 128; n0 = blockIdx.y * 128; }
    else { m0 = blockIdx.y * 128; n0 = blockIdx.x * 128; }

    size_t cofs = 0;
    int k0, k1;
    if constexpr (MAP == 3){
        const int bz = blockIdx.z;
        A += (size_t)bz * (size_t)abatch;
        B += (size_t)bz * (size_t)bbatch;
        bias += (size_t)bz * (size_t)bbias;
        cofs = (size_t)bz * (size_t)cbatch;
        k0 = 0; k1 = kIters;
    } else {
        k0 = blockIdx.z * kChunk;
        k1 = k0 + kChunk; if (k1 > kIters) k1 = kIters;
        if (k0 >= k1) return;
    }

    const int cr = lane >> 2, cp = lane & 3;
    const int ca = wave * 2, cb = wave * 2 + 1;
    const u16* gA0 = A + (size_t)(m0 + ca * 16 + cr) * lda + cp * 8;
    const u16* gA1 = A + (size_t)(m0 + cb * 16 + cr) * lda + cp * 8;
    const u16* gB0 = B + (size_t)(n0 + ca * 16 + cr) * ldb + cp * 8;
    const u16* gB1 = B + (size_t)(n0 + cb * 16 + cr) * ldb + cp * 8;
    u16* lA0 = As + ca * 512;  u16* lA1 = As + cb * 512;
    u16* lB0 = Bs + ca * 512;  u16* lB1 = Bs + cb * 512;

    f32x4 acc[4][4];
    #pragma unroll
    for (int a = 0; a < 4; a++)
        #pragma unroll
        for (int b = 0; b < 4; b++)
            #pragma unroll
            for (int e = 0; e < 4; e++) acc[a][b][e] = 0.f;

    for (int kt = k0; kt < k1; ++kt){
        __syncthreads();
        const size_t ko = (size_t)kt * 32;
        async16(gA0 + ko, lA0);
        async16(gA1 + ko, lA1);
        async16(gB0 + ko, lB0);
        async16(gB1 + ko, lB1);
        __syncthreads();
        bf16x8 af[4], bg[4];
        #pragma unroll
        for (int mi = 0; mi < 4; mi++)
            af[mi] = *reinterpret_cast<const bf16x8*>(
                &As[(wr * 64 + mi * 16 + t) * 32 + q * 8]);
        #pragma unroll
        for (int ni = 0; ni < 4; ni++)
            bg[ni] = *reinterpret_cast<const bf16x8*>(
                &Bs[(wc * 64 + ni * 16 + t) * 32 + q * 8]);
        #pragma unroll
        for (int mi = 0; mi < 4; mi++)
            #pragma unroll
            for (int ni = 0; ni < 4; ni++)
                acc[mi][ni] = __builtin_amdgcn_mfma_f32_16x16x32_bf16(
                    af[mi], bg[ni], acc[mi][ni], 0, 0, 0);
    }

    #pragma unroll
    for (int mi = 0; mi < 4; mi++){
        #pragma unroll
        for (int i = 0; i < 4; i++){
            int m = m0 + wr * 64 + mi * 16 + q * 4 + i;
            float bm = 0.f;
            if constexpr (BIAS_MODE == 1) bm = bias[m];
            #pragma unroll
            for (int ni = 0; ni < 4; ni++){
                int n = n0 + wc * 64 + ni * 16 + t;
                float v = acc[mi][ni][i] + bm;
                if constexpr (BIAS_MODE == 2) v += bias[n];
                if constexpr (RELU) v = (v > 0.f) ? v : 0.f;
                size_t ci = cofs + (size_t)m * ldc + n;
                if constexpr (OUT_MODE == 2) atomicAdd(((float*)Cp) + ci, v);
                else                         ((float*)Cp)[ci] = v;
            }
        }
    }
}

// means[slot][q] = bf16( sums3[slot][q] / counts[slot] )
__global__ void build_means(const float* sums3, const float* counts, u16* means)
{
    int slot = blockIdx.x;               // 0..383
    float c = counts[slot];
    float inv = (c > 0.f) ? 1.f / c : 0.f;
    const float* src = sums3 + (size_t)slot * 1024;
    u16* dst = means + (size_t)slot * 1024;
    #pragma unroll
    for (int i = 0; i < 4; i++){
        int qi = threadIdx.x + i * 256;
        dst[qi] = f2bf(src[qi] * inv);
    }
}

__global__ void build_means_ovf(const float* sumsOvf, const float* counts, u16* mo)
{
    int b = blockIdx.x;                  // bb = branch, os = ovf slot
    int bb = b >> 7, os = b & 127;
    float c = counts[384 + os];
    float inv = (c > 0.f) ? 1.f / c : 0.f;
    const float* src = sumsOvf + (size_t)os * 3072 + (size_t)bb * 1024;
    u16* dst = mo + (size_t)b * 1024;
    #pragma unroll
    for (int i = 0; i < 4; i++){
        int qi = threadIdx.x + i * 256;
        dst[qi] = f2bf(src[qi] * inv);
    }
}

__global__ void select_out(const float* outA, const float* outOvf,
                           const int* labels, const int* slot_of_node,
                           void* dout, const int* flags)
{
    int idx = blockIdx.x * 256 + threadIdx.x;   // < 300*1024
    int n = idx >> 10, r = idx & 1023;
    int slot = slot_of_node[n];
    float v;
    if (slot < 384) v = outA[(size_t)slot * 1024 + r];
    else {
        int k = labels[n];
        v = outOvf[((size_t)k * 128 + (slot - 384)) * 1024 + r];
    }
    if (flags[0]) ((u16*)dout)[idx] = f2bf(v);
    else          ((float*)dout)[idx] = v;
}

// ---------------------------------------------------------------------------
extern "C" void kernel_launch(void* const* d_in, const int* in_sizes, int n_in,
                              void* d_out, int out_size, void* d_ws, size_t ws_size,
                              hipStream_t stream)
{
    constexpr int C = 256, R = 1024, NN = 300, P = 40000;
    constexpr int PPAD = 40064;          // 313 * 128
    constexpr int M1 = 3 * R;            // 3072 L1 rows (branch-major)
    constexpr int SLOTS = 512;           // 3*128 grouped + 128 overflow

    const void* x      = d_in[0];
    const void* masks  = d_in[1];
    const int*  labels = (const int*)d_in[2];
    const void* W1[3] = { d_in[3], d_in[7],  d_in[11] };
    const void* B1[3] = { d_in[4], d_in[8],  d_in[12] };
    const void* W2[3] = { d_in[5], d_in[9],  d_in[13] };
    const void* B2[3] = { d_in[6], d_in[10], d_in[14] };
    (void)in_sizes; (void)n_in; (void)out_size; (void)ws_size;

    char* ws = (char*)d_ws;
    size_t off = 0;
    auto alloc = [&](size_t b)->size_t {
        size_t o = off; off += (b + 255) & ~(size_t)255; return o;
    };

    int*   flags   = (int*)  (ws + alloc(256));
    int*   slotmap = (int*)  (ws + alloc(384 * 4));
    int*   ovfflag = (int*)  (ws + alloc(256));
    u16*   feat    = (u16*)  (ws + alloc((size_t)PPAD * C * 2));    // [p][c]
    u16*   B1T     = (u16*)  (ws + alloc((size_t)M1 * C * 2));      // [m][c]
    float* b1f     = (float*)(ws + alloc((size_t)M1 * 4));
    float* b2f     = (float*)(ws + alloc((size_t)M1 * 4));
    u16*   mfT     = (u16*)  (ws + alloc((size_t)SLOTS * PPAD * 2));// [slot][p]
    // contiguous zero region: sums3 | sumsOvf | counts
    float* sums3   = (float*)(ws + alloc((size_t)384 * 1024 * 4));
    float* sumsOvf = (float*)(ws + alloc((size_t)128 * M1 * 4));
    float* counts  = (float*)(ws + alloc((size_t)SLOTS * 4));
    u16*   means   = (u16*)  (ws + alloc((size_t)384 * R * 2));
    u16*   meansOv = (u16*)  (ws + alloc((size_t)384 * R * 2));
    u16*   W2T     = (u16*)  (ws + alloc((size_t)3 * R * R * 2));
    float* outA    = (float*)(ws + alloc((size_t)384 * R * 4));
    float* outOvf  = (float*)(ws + alloc((size_t)384 * R * 4));

    probe_and_perm<<<2, 320, 0, stream>>>(x, masks, flags, labels, slotmap, ovfflag);
    hipMemsetAsync(mfT, 0, (size_t)SLOTS * PPAD * 2, stream);
    hipMemsetAsync(sums3, 0,
        (size_t)384 * 1024 * 4 + (size_t)128 * M1 * 4 + (size_t)SLOTS * 4, stream);

    trans_cvt_f3<<<dim3(PPAD / 32, C / 32, 1), dim3(32, 8), 0, stream>>>(
        x, x, x, feat, 0, C, P, C, flags);
    trans_cvt_f3<<<dim3(R / 32, C / 32, 3), dim3(32, 8), 0, stream>>>(
        W1[0], W1[1], W1[2], B1T, (size_t)R * C, C, R, C, flags);
    trans_cvt_f3<<<dim3(R / 32, R / 32, 3), dim3(32, 8), 0, stream>>>(
        W2[0], W2[1], W2[2], W2T, (size_t)R * R, R, R, R, flags);
    pack_biases<<<(3 * R + 255) / 256, 256, 0, stream>>>(
        B1[0], B1[1], B1[2], B2[0], B2[1], B2[2], b1f, b2f, flags);
    trans_mask_count<<<dim3(PPAD / 128, 384 / 32), 256, 0, stream>>>(
        masks, mfT, slotmap, counts, flags);

    // fused L1 + mask-sum, 576 ids (48 idle from the mod-8 swizzle padding)
    fused_l1_mask<0><<<576, 256, 0, stream>>>(
        B1T, feat, mfT, b1f, sums3, nullptr);
    // overflow path (skipped unless some label has > 128 nodes)
    fused_l1_mask<1><<<dim3(24, 8), 256, 0, stream>>>(
        B1T, feat, mfT, b1f, sumsOvf, ovfflag);

    build_means<<<384, 256, 0, stream>>>(sums3, counts, means);
    build_means_ovf<<<384, 256, 0, stream>>>(sumsOvf, counts, meansOv);

    // L2 on means, all 3 branches batched via blockIdx.z
    gemm_nt<2, false, 0, 3>
        <<<dim3(R / 128, 1, 3), 256, 0, stream>>>(
            means, R, W2T, R, outA, R, b2f,
            R / 32, R / 32, nullptr,
            (long)128 * R, (long)R * R, (long)128 * R, (long)R);
    gemm_nt<2, false, 0, 3>
        <<<dim3(R / 128, 1, 3), 256, 0, stream>>>(
            meansOv, R, W2T, R, outOvf, R, b2f,
            R / 32, R / 32, ovfflag,
            (long)128 * R, (long)R * R, (long)128 * R, (long)R);

    select_out<<<(NN * R) / 256, 256, 0, stream>>>(
        outA, outOvf, labels, slotmap, d_out, flags);
}